// Round 4
// baseline (240.105 us; speedup 1.0000x reference)
//
#include <hip/hip_runtime.h>

typedef __bf16 bf16x8 __attribute__((ext_vector_type(8)));
typedef __bf16 bf16x4 __attribute__((ext_vector_type(4)));
typedef float f32x4 __attribute__((ext_vector_type(4)));

#define MFMA16(a,b,c) __builtin_amdgcn_mfma_f32_16x16x32_bf16((a),(b),(c),0,0,0)

__device__ __forceinline__ void gload_lds16(const void* g, void* l) {
    __builtin_amdgcn_global_load_lds(
        (const __attribute__((address_space(1))) void*)g,
        (__attribute__((address_space(3))) void*)l, 16, 0, 0);
}

// Problem constants: B=8 S=1024 IN=512 ORIG=64 E=512 H=8 hd=64
// xc: [8192][576]  Wqkv: [1536][576]  Wo: [512][512]
// q_ws/k_ws: [64(bh)][1024(s)][64(d)] bf16 ; vt_ws: [64(bh)][64(d)][1024(s)] bf16

__global__ __launch_bounds__(256) void k_convert(
    const float* __restrict__ x, const float* __restrict__ inp,
    const float* __restrict__ Wqkv, const float* __restrict__ Wo,
    __bf16* __restrict__ xc, __bf16* __restrict__ wq, __bf16* __restrict__ wo)
{
    unsigned i = blockIdx.x * 256u + threadIdx.x;
    const unsigned n1 = 8192u * 576u;
    const unsigned n2 = 1536u * 576u;
    if (i < n1) {
        unsigned m = i / 576u, k = i - m * 576u;
        float v = (k < 512u) ? x[(size_t)m * 512u + k] : inp[(size_t)m * 64u + (k - 512u)];
        xc[i] = (__bf16)v;
    } else if (i < n1 + n2) {
        wq[i - n1] = (__bf16)Wqkv[i - n1];
    } else {
        wo[i - n1 - n2] = (__bf16)Wo[i - n1 - n2];
    }
}

// ---------------- QKV GEMM (m97 structure): 128x128 tile, BK=32, global_load_lds ----------------
__global__ __launch_bounds__(256) void k_qkv_gemm(
    const __bf16* __restrict__ A,    // [8192][576]
    const __bf16* __restrict__ W,    // [1536][576]
    const float* __restrict__ bias,
    __bf16* __restrict__ q_ws, __bf16* __restrict__ k_ws, __bf16* __restrict__ vt_ws)
{
    const int K = 576;
    __shared__ __align__(16) __bf16 As[128][32];   // 8 KB, linear (global_load_lds dest)
    __shared__ __align__(16) __bf16 Bs[128][32];
    int m0 = blockIdx.x * 128, n0 = blockIdx.y * 128;
    int t = threadIdx.x, w = t >> 6, l = t & 63;
    int lo = l & 15, hi = l >> 4;
    int wr = w >> 1, wc = w & 1;

    const __bf16* gA = A + (size_t)(m0 + w * 16 + (l >> 2)) * K + (l & 3) * 8;
    const __bf16* gB = W + (size_t)(n0 + w * 16 + (l >> 2)) * K + (l & 3) * 8;
    char* lA = (char*)&As[0][0] + w * 1024;
    char* lB = (char*)&Bs[0][0] + w * 1024;

    f32x4 acc[4][4] = {};
    for (int k0 = 0; k0 < K; k0 += 32) {
        gload_lds16(gA + k0, lA);
        gload_lds16(gA + 64 * K + k0, lA + 4096);
        gload_lds16(gB + k0, lB);
        gload_lds16(gB + 64 * K + k0, lB + 4096);
        __syncthreads();
        bf16x8 af[4], bq[4];
#pragma unroll
        for (int mi = 0; mi < 4; ++mi) af[mi] = *(const bf16x8*)&As[wr * 64 + mi * 16 + lo][hi * 8];
#pragma unroll
        for (int ni = 0; ni < 4; ++ni) bq[ni] = *(const bf16x8*)&Bs[wc * 64 + ni * 16 + lo][hi * 8];
#pragma unroll
        for (int mi = 0; mi < 4; ++mi)
#pragma unroll
            for (int ni = 0; ni < 4; ++ni)
                acc[mi][ni] = MFMA16(af[mi], bq[ni], acc[mi][ni]);
        __syncthreads();
    }

#pragma unroll
    for (int ni = 0; ni < 4; ++ni) {
        int n = n0 + wc * 64 + ni * 16 + lo;
        int h = n / 192, jj = n % 192, part = jj >> 6, d = jj & 63;
        float bn = bias[n];
#pragma unroll
        for (int mi = 0; mi < 4; ++mi)
#pragma unroll
            for (int j = 0; j < 4; ++j) {
                int m = m0 + wr * 64 + mi * 16 + hi * 4 + j;
                float v = acc[mi][ni][j] + bn;
                int b = m >> 10, s = m & 1023;
                size_t bh = (size_t)(b * 8 + h);
                if (part == 0)      q_ws[(bh * 1024 + s) * 64 + d] = (__bf16)(v * 0.125f);
                else if (part == 1) k_ws[(bh * 1024 + s) * 64 + d] = (__bf16)v;
                else                vt_ws[(bh * 64 + d) * 1024 + s] = (__bf16)v;
            }
    }
}

// ---------------- fused attention v4: register logits, 1-barrier softmax ----------------
__global__ __launch_bounds__(256) void k_attn(
    const __bf16* __restrict__ q_ws, const __bf16* __restrict__ k_ws,
    const __bf16* __restrict__ vt_ws,
    float* __restrict__ att_out, __bf16* __restrict__ values)
{
    __shared__ __align__(16) __bf16 Qs[16][72];      //  2,304 B
    __shared__ __align__(16) __bf16 Ps[4][16][264];  // 33,792 B (row stride 528B)
    __shared__ __align__(16) float Ored[4][16][64];  // 16,384 B
    __shared__ float Sred[4][16][2];                 //    512 B  (mx,sum scratch; no reuse race)

    int bid = blockIdx.x;                  // grid = 4096 (64 bh x 64 q-tiles), XCD-bijective
    int nid = (bid & 7) * 512 + (bid >> 3);
    int bh = nid >> 6, qt = nid & 63;
    int q0 = qt * 16;
    int t = threadIdx.x, w = t >> 6, l = t & 63;
    int lo = l & 15, hi = l >> 4;

    if (t < 128) {
        int r = t >> 3, c = (t & 7) * 8;
        *(bf16x8*)&Qs[r][c] = *(const bf16x8*)&q_ws[((size_t)bh * 1024 + q0 + r) * 64 + c];
    }
    __syncthreads();

    bf16x8 qa0 = *(const bf16x8*)&Qs[lo][hi * 8];
    bf16x8 qa1 = *(const bf16x8*)&Qs[lo][32 + hi * 8];

    // QK^T into registers: lane holds S[q0 + hi*4 + j][w*256 + ct*16 + lo]
    const __bf16* Kb = k_ws + (size_t)bh * 65536;
    f32x4 acc[16];
#pragma unroll
    for (int ct = 0; ct < 16; ++ct) {
        const __bf16* kp = Kb + (size_t)(w * 256 + ct * 16 + lo) * 64 + hi * 8;
        bf16x8 kb0 = *(const bf16x8*)kp;
        bf16x8 kb1 = *(const bf16x8*)(kp + 32);
        f32x4 a = {};
        a = MFMA16(qa0, kb0, a);
        a = MFMA16(qa1, kb1, a);
        acc[ct] = a;
    }

    // per-wave max over this wave's 256-col slice
    f32x4 mx = acc[0];
#pragma unroll
    for (int ct = 1; ct < 16; ++ct)
#pragma unroll
        for (int j = 0; j < 4; ++j) mx[j] = fmaxf(mx[j], acc[ct][j]);
#pragma unroll
    for (int off = 1; off < 16; off <<= 1)
#pragma unroll
        for (int j = 0; j < 4; ++j) mx[j] = fmaxf(mx[j], __shfl_xor(mx[j], off));

    // exp with per-wave max + local sum
    f32x4 sum = {};
#pragma unroll
    for (int ct = 0; ct < 16; ++ct)
#pragma unroll
        for (int j = 0; j < 4; ++j) {
            acc[ct][j] = __expf(acc[ct][j] - mx[j]);
            sum[j] += acc[ct][j];
        }
#pragma unroll
    for (int off = 1; off < 16; off <<= 1)
#pragma unroll
        for (int j = 0; j < 4; ++j) sum[j] += __shfl_xor(sum[j], off);

    if (lo == 0) {
#pragma unroll
        for (int j = 0; j < 4; ++j) {
            Sred[w][hi * 4 + j][0] = mx[j];
            Sred[w][hi * 4 + j][1] = sum[j];
        }
    }
    __syncthreads();

    // combine: gmx across waves, gsum with rescale; scale = exp(mx_w - gmx)/gsum
    f32x4 scale;
#pragma unroll
    for (int j = 0; j < 4; ++j) {
        int r = hi * 4 + j;
        float m0_ = Sred[0][r][0], m1_ = Sred[1][r][0], m2_ = Sred[2][r][0], m3_ = Sred[3][r][0];
        float gmx = fmaxf(fmaxf(m0_, m1_), fmaxf(m2_, m3_));
        float gsum = Sred[0][r][1] * __expf(m0_ - gmx) + Sred[1][r][1] * __expf(m1_ - gmx)
                   + Sred[2][r][1] * __expf(m2_ - gmx) + Sred[3][r][1] * __expf(m3_ - gmx);
        scale[j] = __expf(mx[j] - gmx) / gsum;
    }

    // write probs: f32 -> global (nontemporal), bf16 -> wave-private LDS for PV
    float* gout = att_out + ((size_t)bh * 1024 + q0) * 1024 + w * 256;
#pragma unroll
    for (int ct = 0; ct < 16; ++ct)
#pragma unroll
        for (int j = 0; j < 4; ++j) {
            float p = acc[ct][j] * scale[j];
            __builtin_nontemporal_store(p, &gout[(size_t)(hi * 4 + j) * 1024 + ct * 16 + lo]);
            Ps[w][hi * 4 + j][ct * 16 + lo] = (__bf16)p;
        }

    // PV: partial over this wave's 256-k slice; A = Ps[w], B = V^T
    const __bf16* Vb = vt_ws + (size_t)bh * 65536 + w * 256;
    f32x4 oacc[4] = {};
#pragma unroll
    for (int kc = 0; kc < 8; ++kc) {
        bf16x8 pa = *(const bf16x8*)&Ps[w][lo][kc * 32 + hi * 8];
#pragma unroll
        for (int dt = 0; dt < 4; ++dt) {
            bf16x8 vb = *(const bf16x8*)(Vb + (size_t)(dt * 16 + lo) * 1024 + kc * 32 + hi * 8);
            oacc[dt] = MFMA16(pa, vb, oacc[dt]);
        }
    }
#pragma unroll
    for (int dt = 0; dt < 4; ++dt)
#pragma unroll
        for (int j = 0; j < 4; ++j)
            Ored[w][hi * 4 + j][dt * 16 + lo] = oacc[dt][j];
    __syncthreads();

    {
        int r = t >> 4, d = (t & 15) * 4;
        f32x4 s0 = *(f32x4*)&Ored[0][r][d];
        f32x4 s1 = *(f32x4*)&Ored[1][r][d];
        f32x4 s2 = *(f32x4*)&Ored[2][r][d];
        f32x4 s3 = *(f32x4*)&Ored[3][r][d];
        f32x4 o = (s0 + s1) + (s2 + s3);
        bf16x4 ob;
        ob[0] = (__bf16)o[0]; ob[1] = (__bf16)o[1];
        ob[2] = (__bf16)o[2]; ob[3] = (__bf16)o[3];
        int b = bh >> 3, h = bh & 7;
        *(bf16x4*)&values[((size_t)b * 1024 + q0 + r) * 512 + h * 64 + d] = ob;
    }
}

// ---------------- output GEMM (m97 structure): [8192x512] @ [512x512] + bias ----------------
__global__ __launch_bounds__(256) void k_out_gemm(
    const __bf16* __restrict__ A, const __bf16* __restrict__ W,
    const float* __restrict__ bias, float* __restrict__ out)
{
    const int K = 512;
    __shared__ __align__(16) __bf16 As[128][32];
    __shared__ __align__(16) __bf16 Bs[128][32];
    int m0 = blockIdx.x * 128, n0 = blockIdx.y * 128;
    int t = threadIdx.x, w = t >> 6, l = t & 63;
    int lo = l & 15, hi = l >> 4;
    int wr = w >> 1, wc = w & 1;

    const __bf16* gA = A + (size_t)(m0 + w * 16 + (l >> 2)) * K + (l & 3) * 8;
    const __bf16* gB = W + (size_t)(n0 + w * 16 + (l >> 2)) * K + (l & 3) * 8;
    char* lA = (char*)&As[0][0] + w * 1024;
    char* lB = (char*)&Bs[0][0] + w * 1024;

    f32x4 acc[4][4] = {};
    for (int k0 = 0; k0 < K; k0 += 32) {
        gload_lds16(gA + k0, lA);
        gload_lds16(gA + 64 * K + k0, lA + 4096);
        gload_lds16(gB + k0, lB);
        gload_lds16(gB + 64 * K + k0, lB + 4096);
        __syncthreads();
        bf16x8 af[4], bq[4];
#pragma unroll
        for (int mi = 0; mi < 4; ++mi) af[mi] = *(const bf16x8*)&As[wr * 64 + mi * 16 + lo][hi * 8];
#pragma unroll
        for (int ni = 0; ni < 4; ++ni) bq[ni] = *(const bf16x8*)&Bs[wc * 64 + ni * 16 + lo][hi * 8];
#pragma unroll
        for (int mi = 0; mi < 4; ++mi)
#pragma unroll
            for (int ni = 0; ni < 4; ++ni)
                acc[mi][ni] = MFMA16(af[mi], bq[ni], acc[mi][ni]);
        __syncthreads();
    }

#pragma unroll
    for (int ni = 0; ni < 4; ++ni) {
        int n = n0 + wc * 64 + ni * 16 + lo;
        float bn = bias[n];
#pragma unroll
        for (int mi = 0; mi < 4; ++mi)
#pragma unroll
            for (int j = 0; j < 4; ++j) {
                int m = m0 + wr * 64 + mi * 16 + hi * 4 + j;
                out[(size_t)m * 512 + n] = acc[mi][ni][j] + bn;
            }
    }
}

extern "C" void kernel_launch(void* const* d_in, const int* in_sizes, int n_in,
                              void* d_out, int out_size, void* d_ws, size_t ws_size,
                              hipStream_t stream)
{
    const float* x    = (const float*)d_in[0];
    const float* inp  = (const float*)d_in[1];
    const float* Wqkv = (const float*)d_in[2];
    const float* bqkv = (const float*)d_in[3];
    const float* Wo   = (const float*)d_in[4];
    const float* bo   = (const float*)d_in[5];

    float* out_o   = (float*)d_out;                    // [8,1024,512]
    float* out_att = out_o + (size_t)8 * 1024 * 512;   // [8,8,1024,1024]

    char* ws = (char*)d_ws;
    __bf16* xc    = (__bf16*)(ws + 0);
    __bf16* wq    = (__bf16*)(ws + 9437184);
    __bf16* wo    = (__bf16*)(ws + 11206656);
    __bf16* q_ws  = (__bf16*)(ws + 11730944);
    __bf16* k_ws  = (__bf16*)(ws + 20119552);
    __bf16* vt_ws = (__bf16*)(ws + 28508160);
    __bf16* vals  = (__bf16*)(ws + 36896768);

    k_convert<<<22912, 256, 0, stream>>>(x, inp, Wqkv, Wo, xc, wq, wo);
    k_qkv_gemm<<<dim3(64, 12), 256, 0, stream>>>(xc, wq, bqkv, q_ws, k_ws, vt_ws);
    k_attn<<<4096, 256, 0, stream>>>(q_ws, k_ws, vt_ws, out_att, vals);
    k_out_gemm<<<dim3(64, 4), 256, 0, stream>>>(vals, wo, bo, out_o);
}

// Round 5
// 184.746 us; speedup vs baseline: 1.2996x; 1.2996x over previous
//
#include <hip/hip_runtime.h>

typedef __bf16 bf16x8 __attribute__((ext_vector_type(8)));
typedef __bf16 bf16x4 __attribute__((ext_vector_type(4)));
typedef float f32x4 __attribute__((ext_vector_type(4)));

#define MFMA16(a,b,c) __builtin_amdgcn_mfma_f32_16x16x32_bf16((a),(b),(c),0,0,0)

__device__ __forceinline__ void gload_lds16(const void* g, void* l) {
    __builtin_amdgcn_global_load_lds(
        (const __attribute__((address_space(1))) void*)g,
        (__attribute__((address_space(3))) void*)l, 16, 0, 0);
}

// Problem constants: B=8 S=1024 IN=512 ORIG=64 E=512 H=8 hd=64
// xc: [8192][576]  Wqkv: [1536][576]  Wo: [512][512]
// q_ws/k_ws: [64(bh)][1024(s)][64(d)] bf16 ; vt_ws: [64(bh)][64(d)][1024(s)] bf16

__global__ __launch_bounds__(256) void k_convert(
    const float* __restrict__ x, const float* __restrict__ inp,
    const float* __restrict__ Wqkv, const float* __restrict__ Wo,
    __bf16* __restrict__ xc, __bf16* __restrict__ wq, __bf16* __restrict__ wo)
{
    unsigned i = blockIdx.x * 256u + threadIdx.x;
    const unsigned n1 = 8192u * 576u;
    const unsigned n2 = 1536u * 576u;
    if (i < n1) {
        unsigned m = i / 576u, k = i - m * 576u;
        float v = (k < 512u) ? x[(size_t)m * 512u + k] : inp[(size_t)m * 64u + (k - 512u)];
        xc[i] = (__bf16)v;
    } else if (i < n1 + n2) {
        wq[i - n1] = (__bf16)Wqkv[i - n1];
    } else {
        wo[i - n1 - n2] = (__bf16)Wo[i - n1 - n2];
    }
}

// ---------------- QKV GEMM (m97 structure): 128x128 tile, BK=32, global_load_lds ----------------
__global__ __launch_bounds__(256) void k_qkv_gemm(
    const __bf16* __restrict__ A, const __bf16* __restrict__ W,
    const float* __restrict__ bias,
    __bf16* __restrict__ q_ws, __bf16* __restrict__ k_ws, __bf16* __restrict__ vt_ws)
{
    const int K = 576;
    __shared__ __align__(16) __bf16 As[128][32];
    __shared__ __align__(16) __bf16 Bs[128][32];
    int m0 = blockIdx.x * 128, n0 = blockIdx.y * 128;
    int t = threadIdx.x, w = t >> 6, l = t & 63;
    int lo = l & 15, hi = l >> 4;
    int wr = w >> 1, wc = w & 1;

    const __bf16* gA = A + (size_t)(m0 + w * 16 + (l >> 2)) * K + (l & 3) * 8;
    const __bf16* gB = W + (size_t)(n0 + w * 16 + (l >> 2)) * K + (l & 3) * 8;
    char* lA = (char*)&As[0][0] + w * 1024;
    char* lB = (char*)&Bs[0][0] + w * 1024;

    f32x4 acc[4][4] = {};
    for (int k0 = 0; k0 < K; k0 += 32) {
        gload_lds16(gA + k0, lA);
        gload_lds16(gA + 64 * K + k0, lA + 4096);
        gload_lds16(gB + k0, lB);
        gload_lds16(gB + 64 * K + k0, lB + 4096);
        __syncthreads();
        bf16x8 af[4], bq[4];
#pragma unroll
        for (int mi = 0; mi < 4; ++mi) af[mi] = *(const bf16x8*)&As[wr * 64 + mi * 16 + lo][hi * 8];
#pragma unroll
        for (int ni = 0; ni < 4; ++ni) bq[ni] = *(const bf16x8*)&Bs[wc * 64 + ni * 16 + lo][hi * 8];
#pragma unroll
        for (int mi = 0; mi < 4; ++mi)
#pragma unroll
            for (int ni = 0; ni < 4; ++ni)
                acc[mi][ni] = MFMA16(af[mi], bq[ni], acc[mi][ni]);
        __syncthreads();
    }

#pragma unroll
    for (int ni = 0; ni < 4; ++ni) {
        int n = n0 + wc * 64 + ni * 16 + lo;
        int h = n / 192, jj = n % 192, part = jj >> 6, d = jj & 63;
        float bn = bias[n];
#pragma unroll
        for (int mi = 0; mi < 4; ++mi)
#pragma unroll
            for (int j = 0; j < 4; ++j) {
                int m = m0 + wr * 64 + mi * 16 + hi * 4 + j;
                float v = acc[mi][ni][j] + bn;
                int b = m >> 10, s = m & 1023;
                size_t bh = (size_t)(b * 8 + h);
                if (part == 0)      q_ws[(bh * 1024 + s) * 64 + d] = (__bf16)(v * 0.125f);
                else if (part == 1) k_ws[(bh * 1024 + s) * 64 + d] = (__bf16)v;
                else                vt_ws[(bh * 64 + d) * 1024 + s] = (__bf16)v;
            }
    }
}

// ---------------- fused attention v5: stores-last, full-line coalesced att writes ----------------
__global__ __launch_bounds__(256, 3) void k_attn(
    const __bf16* __restrict__ q_ws, const __bf16* __restrict__ k_ws,
    const __bf16* __restrict__ vt_ws,
    float* __restrict__ att_out, __bf16* __restrict__ values)
{
    __shared__ __align__(16) __bf16 Qs[16][72];      //  2,304 B
    __shared__ __align__(16) __bf16 Ps[4][16][264];  // 33,792 B  exp(s - mx_w), UNSCALED
    __shared__ __align__(16) float Ored[4][16][64];  // 16,384 B
    __shared__ float Sred[4][16][2];                 //    512 B  -> ~53 KB, 3 blk/CU

    int bid = blockIdx.x;                  // grid = 4096, XCD-bijective swizzle
    int nid = (bid & 7) * 512 + (bid >> 3);
    int bh = nid >> 6, qt = nid & 63;
    int q0 = qt * 16;
    int t = threadIdx.x, w = t >> 6, l = t & 63;
    int lo = l & 15, hi = l >> 4;

    if (t < 128) {
        int r = t >> 3, c = (t & 7) * 8;
        *(bf16x8*)&Qs[r][c] = *(const bf16x8*)&q_ws[((size_t)bh * 1024 + q0 + r) * 64 + c];
    }
    __syncthreads();

    bf16x8 qa0 = *(const bf16x8*)&Qs[lo][hi * 8];
    bf16x8 qa1 = *(const bf16x8*)&Qs[lo][32 + hi * 8];

    // QK^T into registers: lane holds S[q0 + hi*4 + j][w*256 + ct*16 + lo]
    const __bf16* Kb = k_ws + (size_t)bh * 65536;
    f32x4 acc[16];
#pragma unroll
    for (int ct = 0; ct < 16; ++ct) {
        const __bf16* kp = Kb + (size_t)(w * 256 + ct * 16 + lo) * 64 + hi * 8;
        bf16x8 kb0 = *(const bf16x8*)kp;
        bf16x8 kb1 = *(const bf16x8*)(kp + 32);
        f32x4 a = {};
        a = MFMA16(qa0, kb0, a);
        a = MFMA16(qa1, kb1, a);
        acc[ct] = a;
    }

    // wave-local softmax stats over this wave's 256-col slice
    f32x4 mx = acc[0];
#pragma unroll
    for (int ct = 1; ct < 16; ++ct)
#pragma unroll
        for (int j = 0; j < 4; ++j) mx[j] = fmaxf(mx[j], acc[ct][j]);
#pragma unroll
    for (int off = 1; off < 16; off <<= 1)
#pragma unroll
        for (int j = 0; j < 4; ++j) mx[j] = fmaxf(mx[j], __shfl_xor(mx[j], off));

    f32x4 sum = {};
#pragma unroll
    for (int ct = 0; ct < 16; ++ct)
#pragma unroll
        for (int j = 0; j < 4; ++j) {
            acc[ct][j] = __expf(acc[ct][j] - mx[j]);
            sum[j] += acc[ct][j];
        }
#pragma unroll
    for (int off = 1; off < 16; off <<= 1)
#pragma unroll
        for (int j = 0; j < 4; ++j) sum[j] += __shfl_xor(sum[j], off);

    // stage UNSCALED exp to LDS (bf16) + publish (mx, sum)
#pragma unroll
    for (int ct = 0; ct < 16; ++ct)
#pragma unroll
        for (int j = 0; j < 4; ++j)
            Ps[w][hi * 4 + j][ct * 16 + lo] = (__bf16)acc[ct][j];
    if (lo == 0) {
#pragma unroll
        for (int j = 0; j < 4; ++j) {
            Sred[w][hi * 4 + j][0] = mx[j];
            Sred[w][hi * 4 + j][1] = sum[j];
        }
    }
    __syncthreads();

    // per-row global max; fac = exp(mx_w - gmx) for THIS wave's rescale
    f32x4 fac;
#pragma unroll
    for (int j = 0; j < 4; ++j) {
        int r = hi * 4 + j;
        float gmx = fmaxf(fmaxf(Sred[0][r][0], Sred[1][r][0]),
                          fmaxf(Sred[2][r][0], Sred[3][r][0]));
        fac[j] = __expf(mx[j] - gmx);
    }

    // PV on unscaled probs (LDS + L2-resident V^T); rescale folded into Ored
    const __bf16* Vb = vt_ws + (size_t)bh * 65536 + w * 256;
    f32x4 oacc[4] = {};
#pragma unroll
    for (int kc = 0; kc < 8; ++kc) {
        bf16x8 pa = *(const bf16x8*)&Ps[w][lo][kc * 32 + hi * 8];
#pragma unroll
        for (int dt = 0; dt < 4; ++dt) {
            bf16x8 vb = *(const bf16x8*)(Vb + (size_t)(dt * 16 + lo) * 1024 + kc * 32 + hi * 8);
            oacc[dt] = MFMA16(pa, vb, oacc[dt]);
        }
    }
#pragma unroll
    for (int dt = 0; dt < 4; ++dt)
#pragma unroll
        for (int j = 0; j < 4; ++j)
            Ored[w][hi * 4 + j][dt * 16 + lo] = oacc[dt][j] * fac[j];
    __syncthreads();

    // values: cross-wave reduce, / gsum, store bf16
    {
        int r = t >> 4, d = (t & 15) * 4;
        float m0_ = Sred[0][r][0], m1_ = Sred[1][r][0], m2_ = Sred[2][r][0], m3_ = Sred[3][r][0];
        float gmx = fmaxf(fmaxf(m0_, m1_), fmaxf(m2_, m3_));
        float gsum = Sred[0][r][1] * __expf(m0_ - gmx) + Sred[1][r][1] * __expf(m1_ - gmx)
                   + Sred[2][r][1] * __expf(m2_ - gmx) + Sred[3][r][1] * __expf(m3_ - gmx);
        float ginv = 1.f / gsum;
        f32x4 s0 = *(f32x4*)&Ored[0][r][d];
        f32x4 s1 = *(f32x4*)&Ored[1][r][d];
        f32x4 s2 = *(f32x4*)&Ored[2][r][d];
        f32x4 s3 = *(f32x4*)&Ored[3][r][d];
        f32x4 o = ((s0 + s1) + (s2 + s3)) * ginv;
        bf16x4 ob;
        ob[0] = (__bf16)o[0]; ob[1] = (__bf16)o[1];
        ob[2] = (__bf16)o[2]; ob[3] = (__bf16)o[3];
        int b = bh >> 3, h = bh & 7;
        *(bf16x4*)&values[((size_t)b * 1024 + q0 + r) * 512 + h * 64 + d] = ob;
    }

    // attention f32 output LAST: wave w -> rows [w*4, w*4+4), fully coalesced nt stores
#pragma unroll
    for (int rr = 0; rr < 4; ++rr) {
        int r = w * 4 + rr;
        float m0_ = Sred[0][r][0], m1_ = Sred[1][r][0], m2_ = Sred[2][r][0], m3_ = Sred[3][r][0];
        float gmx = fmaxf(fmaxf(m0_, m1_), fmaxf(m2_, m3_));
        float gsum = Sred[0][r][1] * __expf(m0_ - gmx) + Sred[1][r][1] * __expf(m1_ - gmx)
                   + Sred[2][r][1] * __expf(m2_ - gmx) + Sred[3][r][1] * __expf(m3_ - gmx);
        float ginv = 1.f / gsum;
        float sc[4] = { __expf(m0_ - gmx) * ginv, __expf(m1_ - gmx) * ginv,
                        __expf(m2_ - gmx) * ginv, __expf(m3_ - gmx) * ginv };
        float* gout = att_out + ((size_t)bh * 1024 + q0 + r) * 1024;
#pragma unroll
        for (int it = 0; it < 4; ++it) {
            bf16x4 pb = *(const bf16x4*)&Ps[it][r][l * 4];
            f32x4 p;
            p[0] = (float)pb[0] * sc[it];
            p[1] = (float)pb[1] * sc[it];
            p[2] = (float)pb[2] * sc[it];
            p[3] = (float)pb[3] * sc[it];
            __builtin_nontemporal_store(p, (f32x4*)&gout[it * 256 + l * 4]);
        }
    }
}

// ---------------- output GEMM (m97 structure): [8192x512] @ [512x512] + bias ----------------
__global__ __launch_bounds__(256) void k_out_gemm(
    const __bf16* __restrict__ A, const __bf16* __restrict__ W,
    const float* __restrict__ bias, float* __restrict__ out)
{
    const int K = 512;
    __shared__ __align__(16) __bf16 As[128][32];
    __shared__ __align__(16) __bf16 Bs[128][32];
    int m0 = blockIdx.x * 128, n0 = blockIdx.y * 128;
    int t = threadIdx.x, w = t >> 6, l = t & 63;
    int lo = l & 15, hi = l >> 4;
    int wr = w >> 1, wc = w & 1;

    const __bf16* gA = A + (size_t)(m0 + w * 16 + (l >> 2)) * K + (l & 3) * 8;
    const __bf16* gB = W + (size_t)(n0 + w * 16 + (l >> 2)) * K + (l & 3) * 8;
    char* lA = (char*)&As[0][0] + w * 1024;
    char* lB = (char*)&Bs[0][0] + w * 1024;

    f32x4 acc[4][4] = {};
    for (int k0 = 0; k0 < K; k0 += 32) {
        gload_lds16(gA + k0, lA);
        gload_lds16(gA + 64 * K + k0, lA + 4096);
        gload_lds16(gB + k0, lB);
        gload_lds16(gB + 64 * K + k0, lB + 4096);
        __syncthreads();
        bf16x8 af[4], bq[4];
#pragma unroll
        for (int mi = 0; mi < 4; ++mi) af[mi] = *(const bf16x8*)&As[wr * 64 + mi * 16 + lo][hi * 8];
#pragma unroll
        for (int ni = 0; ni < 4; ++ni) bq[ni] = *(const bf16x8*)&Bs[wc * 64 + ni * 16 + lo][hi * 8];
#pragma unroll
        for (int mi = 0; mi < 4; ++mi)
#pragma unroll
            for (int ni = 0; ni < 4; ++ni)
                acc[mi][ni] = MFMA16(af[mi], bq[ni], acc[mi][ni]);
        __syncthreads();
    }

#pragma unroll
    for (int ni = 0; ni < 4; ++ni) {
        int n = n0 + wc * 64 + ni * 16 + lo;
        float bn = bias[n];
#pragma unroll
        for (int mi = 0; mi < 4; ++mi)
#pragma unroll
            for (int j = 0; j < 4; ++j) {
                int m = m0 + wr * 64 + mi * 16 + hi * 4 + j;
                out[(size_t)m * 512 + n] = acc[mi][ni][j] + bn;
            }
    }
}

extern "C" void kernel_launch(void* const* d_in, const int* in_sizes, int n_in,
                              void* d_out, int out_size, void* d_ws, size_t ws_size,
                              hipStream_t stream)
{
    const float* x    = (const float*)d_in[0];
    const float* inp  = (const float*)d_in[1];
    const float* Wqkv = (const float*)d_in[2];
    const float* bqkv = (const float*)d_in[3];
    const float* Wo   = (const float*)d_in[4];
    const float* bo   = (const float*)d_in[5];

    float* out_o   = (float*)d_out;                    // [8,1024,512]
    float* out_att = out_o + (size_t)8 * 1024 * 512;   // [8,8,1024,1024]

    char* ws = (char*)d_ws;
    __bf16* xc    = (__bf16*)(ws + 0);
    __bf16* wq    = (__bf16*)(ws + 9437184);
    __bf16* wo    = (__bf16*)(ws + 11206656);
    __bf16* q_ws  = (__bf16*)(ws + 11730944);
    __bf16* k_ws  = (__bf16*)(ws + 20119552);
    __bf16* vt_ws = (__bf16*)(ws + 28508160);
    __bf16* vals  = (__bf16*)(ws + 36896768);

    k_convert<<<22912, 256, 0, stream>>>(x, inp, Wqkv, Wo, xc, wq, wo);
    k_qkv_gemm<<<dim3(64, 12), 256, 0, stream>>>(xc, wq, bqkv, q_ws, k_ws, vt_ws);
    k_attn<<<4096, 256, 0, stream>>>(q_ws, k_ws, vt_ws, out_att, vals);
    k_out_gemm<<<dim3(64, 4), 256, 0, stream>>>(vals, wo, bo, out_o);
}

// Round 6
// 180.553 us; speedup vs baseline: 1.3298x; 1.0232x over previous
//
#include <hip/hip_runtime.h>

typedef __bf16 bf16x8 __attribute__((ext_vector_type(8)));
typedef __bf16 bf16x4 __attribute__((ext_vector_type(4)));
typedef float f32x4 __attribute__((ext_vector_type(4)));

#define MFMA16(a,b,c) __builtin_amdgcn_mfma_f32_16x16x32_bf16((a),(b),(c),0,0,0)

__device__ __forceinline__ void gload_lds16(const void* g, void* l) {
    __builtin_amdgcn_global_load_lds(
        (const __attribute__((address_space(1))) void*)g,
        (__attribute__((address_space(3))) void*)l, 16, 0, 0);
}

// Problem constants: B=8 S=1024 IN=512 ORIG=64 E=512 H=8 hd=64
// xc: [8192][576]  Wqkv: [1536][576]  Wo: [512][512]
// q_ws/k_ws: [64(bh)][1024(s)][64(d)] bf16 ; vt_ws: [64(bh)][64(d)][1024(s)] bf16

__global__ __launch_bounds__(256) void k_convert(
    const float* __restrict__ x, const float* __restrict__ inp,
    const float* __restrict__ Wqkv, const float* __restrict__ Wo,
    __bf16* __restrict__ xc, __bf16* __restrict__ wq, __bf16* __restrict__ wo)
{
    const unsigned C1 = 589824u;   // 8192*576/8
    const unsigned C2 = 110592u;   // 1536*576/8
    unsigned i = blockIdx.x * 256u + threadIdx.x;   // 8-element chunk index
    if (i < C1) {
        unsigned e = i * 8u;
        unsigned m = e / 576u, k = e - m * 576u;
        const float* p = (k < 512u) ? x + (size_t)m * 512u + k
                                    : inp + (size_t)m * 64u + (k - 512u);
        f32x4 a = *(const f32x4*)p, b = *(const f32x4*)(p + 4);
        bf16x8 o;
#pragma unroll
        for (int j = 0; j < 4; ++j) { o[j] = (__bf16)a[j]; o[j + 4] = (__bf16)b[j]; }
        *(bf16x8*)&xc[e] = o;
    } else if (i < C1 + C2) {
        unsigned e = (i - C1) * 8u;
        f32x4 a = *(const f32x4*)&Wqkv[e], b = *(const f32x4*)&Wqkv[e + 4];
        bf16x8 o;
#pragma unroll
        for (int j = 0; j < 4; ++j) { o[j] = (__bf16)a[j]; o[j + 4] = (__bf16)b[j]; }
        *(bf16x8*)&wq[e] = o;
    } else {
        unsigned e = (i - C1 - C2) * 8u;
        f32x4 a = *(const f32x4*)&Wo[e], b = *(const f32x4*)&Wo[e + 4];
        bf16x8 o;
#pragma unroll
        for (int j = 0; j < 4; ++j) { o[j] = (__bf16)a[j]; o[j + 4] = (__bf16)b[j]; }
        *(bf16x8*)&wo[e] = o;
    }
}

// ---------------- QKV GEMM (m97 structure): 128x128 tile, BK=32, global_load_lds ----------------
__global__ __launch_bounds__(256) void k_qkv_gemm(
    const __bf16* __restrict__ A, const __bf16* __restrict__ W,
    const float* __restrict__ bias,
    __bf16* __restrict__ q_ws, __bf16* __restrict__ k_ws, __bf16* __restrict__ vt_ws)
{
    const int K = 576;
    __shared__ __align__(16) __bf16 As[128][32];
    __shared__ __align__(16) __bf16 Bs[128][32];
    int m0 = blockIdx.x * 128, n0 = blockIdx.y * 128;
    int t = threadIdx.x, w = t >> 6, l = t & 63;
    int lo = l & 15, hi = l >> 4;
    int wr = w >> 1, wc = w & 1;

    const __bf16* gA = A + (size_t)(m0 + w * 16 + (l >> 2)) * K + (l & 3) * 8;
    const __bf16* gB = W + (size_t)(n0 + w * 16 + (l >> 2)) * K + (l & 3) * 8;
    char* lA = (char*)&As[0][0] + w * 1024;
    char* lB = (char*)&Bs[0][0] + w * 1024;

    f32x4 acc[4][4] = {};
    for (int k0 = 0; k0 < K; k0 += 32) {
        gload_lds16(gA + k0, lA);
        gload_lds16(gA + 64 * K + k0, lA + 4096);
        gload_lds16(gB + k0, lB);
        gload_lds16(gB + 64 * K + k0, lB + 4096);
        __syncthreads();
        bf16x8 af[4], bq[4];
#pragma unroll
        for (int mi = 0; mi < 4; ++mi) af[mi] = *(const bf16x8*)&As[wr * 64 + mi * 16 + lo][hi * 8];
#pragma unroll
        for (int ni = 0; ni < 4; ++ni) bq[ni] = *(const bf16x8*)&Bs[wc * 64 + ni * 16 + lo][hi * 8];
#pragma unroll
        for (int mi = 0; mi < 4; ++mi)
#pragma unroll
            for (int ni = 0; ni < 4; ++ni)
                acc[mi][ni] = MFMA16(af[mi], bq[ni], acc[mi][ni]);
        __syncthreads();
    }

#pragma unroll
    for (int ni = 0; ni < 4; ++ni) {
        int n = n0 + wc * 64 + ni * 16 + lo;
        int h = n / 192, jj = n % 192, part = jj >> 6, d = jj & 63;
        float bn = bias[n];
#pragma unroll
        for (int mi = 0; mi < 4; ++mi)
#pragma unroll
            for (int j = 0; j < 4; ++j) {
                int m = m0 + wr * 64 + mi * 16 + hi * 4 + j;
                float v = acc[mi][ni][j] + bn;
                int b = m >> 10, s = m & 1023;
                size_t bh = (size_t)(b * 8 + h);
                if (part == 0)      q_ws[(bh * 1024 + s) * 64 + d] = (__bf16)(v * 0.125f);
                else if (part == 1) k_ws[(bh * 1024 + s) * 64 + d] = (__bf16)v;
                else                vt_ws[(bh * 64 + d) * 1024 + s] = (__bf16)v;
            }
    }
}

// ---------------- fused attention v6: final probs in LDS, PV-by-d, 2 barriers, 4 blk/CU ----------------
__global__ __launch_bounds__(256, 4) void k_attn(
    const __bf16* __restrict__ q_ws, const __bf16* __restrict__ k_ws,
    const __bf16* __restrict__ vt_ws,
    float* __restrict__ att_out, __bf16* __restrict__ values)
{
    __shared__ __align__(16) __bf16 Ps[4][16][272];  // 34,816 B (row stride 544B)
    __shared__ float Sred[4][16][2];                 //    512 B -> ~34.5 KB, 4 blk/CU

    int bid = blockIdx.x;                  // grid = 4096, XCD-bijective swizzle
    int nid = (bid & 7) * 512 + (bid >> 3);
    int bh = nid >> 6, qt = nid & 63;
    int q0 = qt * 16;
    int t = threadIdx.x, w = t >> 6, l = t & 63;
    int lo = l & 15, hi = l >> 4;

    // Q fragments straight from global (L2-hot), no LDS stage / no barrier
    const __bf16* Qg = q_ws + ((size_t)bh * 1024 + q0 + lo) * 64 + hi * 8;
    bf16x8 qa0 = *(const bf16x8*)Qg;
    bf16x8 qa1 = *(const bf16x8*)(Qg + 32);

    // QK^T into registers: lane holds S[q0 + hi*4 + j][w*256 + ct*16 + lo]
    const __bf16* Kb = k_ws + (size_t)bh * 65536;
    f32x4 acc[16];
#pragma unroll
    for (int ct = 0; ct < 16; ++ct) {
        const __bf16* kp = Kb + (size_t)(w * 256 + ct * 16 + lo) * 64 + hi * 8;
        bf16x8 kb0 = *(const bf16x8*)kp;
        bf16x8 kb1 = *(const bf16x8*)(kp + 32);
        f32x4 a = {};
        a = MFMA16(qa0, kb0, a);
        a = MFMA16(qa1, kb1, a);
        acc[ct] = a;
    }

    // wave-local stats over this wave's 256-col slice
    f32x4 mx = acc[0];
#pragma unroll
    for (int ct = 1; ct < 16; ++ct)
#pragma unroll
        for (int j = 0; j < 4; ++j) mx[j] = fmaxf(mx[j], acc[ct][j]);
#pragma unroll
    for (int off = 1; off < 16; off <<= 1)
#pragma unroll
        for (int j = 0; j < 4; ++j) mx[j] = fmaxf(mx[j], __shfl_xor(mx[j], off));

    f32x4 sum = {};
#pragma unroll
    for (int ct = 0; ct < 16; ++ct)
#pragma unroll
        for (int j = 0; j < 4; ++j) {
            acc[ct][j] = __expf(acc[ct][j] - mx[j]);
            sum[j] += acc[ct][j];
        }
#pragma unroll
    for (int off = 1; off < 16; off <<= 1)
#pragma unroll
        for (int j = 0; j < 4; ++j) sum[j] += __shfl_xor(sum[j], off);

    if (lo == 0) {
#pragma unroll
        for (int j = 0; j < 4; ++j) {
            Sred[w][hi * 4 + j][0] = mx[j];
            Sred[w][hi * 4 + j][1] = sum[j];
        }
    }
    __syncthreads();

    // full softmax scale for this wave's rows: exp(mx_w - gmx)/gsum
    f32x4 scale;
#pragma unroll
    for (int j = 0; j < 4; ++j) {
        int r = hi * 4 + j;
        float m0_ = Sred[0][r][0], m1_ = Sred[1][r][0], m2_ = Sred[2][r][0], m3_ = Sred[3][r][0];
        float gmx = fmaxf(fmaxf(m0_, m1_), fmaxf(m2_, m3_));
        float gsum = Sred[0][r][1] * __expf(m0_ - gmx) + Sred[1][r][1] * __expf(m1_ - gmx)
                   + Sred[2][r][1] * __expf(m2_ - gmx) + Sred[3][r][1] * __expf(m3_ - gmx);
        scale[j] = __expf(mx[j] - gmx) / gsum;
    }

    // Ps = FINAL probs (bf16)
#pragma unroll
    for (int ct = 0; ct < 16; ++ct)
#pragma unroll
        for (int j = 0; j < 4; ++j)
            Ps[w][hi * 4 + j][ct * 16 + lo] = (__bf16)(acc[ct][j] * scale[j]);
    __syncthreads();

    // PV by d: wave w -> d-cols [w*16, w*16+16), all 1024 k across the 4 Ps slices
    const __bf16* Vb = vt_ws + (size_t)bh * 65536 + (size_t)(w * 16 + lo) * 1024 + hi * 8;
    f32x4 oacc = {};
#pragma unroll
    for (int kc = 0; kc < 32; ++kc) {
        bf16x8 pa = *(const bf16x8*)&Ps[kc >> 3][lo][(kc & 7) * 32 + hi * 8];
        bf16x8 vb = *(const bf16x8*)(Vb + kc * 32);
        oacc = MFMA16(pa, vb, oacc);
    }
    int b = bh >> 3, h = bh & 7;
#pragma unroll
    for (int j = 0; j < 4; ++j)
        values[((size_t)b * 1024 + q0 + hi * 4 + j) * 512 + h * 64 + w * 16 + lo] = (__bf16)oacc[j];

    // attention f32 output: wave w -> rows [w*4, w*4+4), full-line coalesced nt stores
#pragma unroll
    for (int rr = 0; rr < 4; ++rr) {
        int r = w * 4 + rr;
        float* gout = att_out + ((size_t)bh * 1024 + q0 + r) * 1024;
#pragma unroll
        for (int it = 0; it < 4; ++it) {
            bf16x4 pb = *(const bf16x4*)&Ps[it][r][l * 4];
            f32x4 p;
            p[0] = (float)pb[0]; p[1] = (float)pb[1];
            p[2] = (float)pb[2]; p[3] = (float)pb[3];
            __builtin_nontemporal_store(p, (f32x4*)&gout[it * 256 + l * 4]);
        }
    }
}

// ---------------- output GEMM (m97 structure): [8192x512] @ [512x512] + bias ----------------
__global__ __launch_bounds__(256) void k_out_gemm(
    const __bf16* __restrict__ A, const __bf16* __restrict__ W,
    const float* __restrict__ bias, float* __restrict__ out)
{
    const int K = 512;
    __shared__ __align__(16) __bf16 As[128][32];
    __shared__ __align__(16) __bf16 Bs[128][32];
    int m0 = blockIdx.x * 128, n0 = blockIdx.y * 128;
    int t = threadIdx.x, w = t >> 6, l = t & 63;
    int lo = l & 15, hi = l >> 4;
    int wr = w >> 1, wc = w & 1;

    const __bf16* gA = A + (size_t)(m0 + w * 16 + (l >> 2)) * K + (l & 3) * 8;
    const __bf16* gB = W + (size_t)(n0 + w * 16 + (l >> 2)) * K + (l & 3) * 8;
    char* lA = (char*)&As[0][0] + w * 1024;
    char* lB = (char*)&Bs[0][0] + w * 1024;

    f32x4 acc[4][4] = {};
    for (int k0 = 0; k0 < K; k0 += 32) {
        gload_lds16(gA + k0, lA);
        gload_lds16(gA + 64 * K + k0, lA + 4096);
        gload_lds16(gB + k0, lB);
        gload_lds16(gB + 64 * K + k0, lB + 4096);
        __syncthreads();
        bf16x8 af[4], bq[4];
#pragma unroll
        for (int mi = 0; mi < 4; ++mi) af[mi] = *(const bf16x8*)&As[wr * 64 + mi * 16 + lo][hi * 8];
#pragma unroll
        for (int ni = 0; ni < 4; ++ni) bq[ni] = *(const bf16x8*)&Bs[wc * 64 + ni * 16 + lo][hi * 8];
#pragma unroll
        for (int mi = 0; mi < 4; ++mi)
#pragma unroll
            for (int ni = 0; ni < 4; ++ni)
                acc[mi][ni] = MFMA16(af[mi], bq[ni], acc[mi][ni]);
        __syncthreads();
    }

#pragma unroll
    for (int ni = 0; ni < 4; ++ni) {
        int n = n0 + wc * 64 + ni * 16 + lo;
        float bn = bias[n];
#pragma unroll
        for (int mi = 0; mi < 4; ++mi)
#pragma unroll
            for (int j = 0; j < 4; ++j) {
                int m = m0 + wr * 64 + mi * 16 + hi * 4 + j;
                out[(size_t)m * 512 + n] = acc[mi][ni][j] + bn;
            }
    }
}

extern "C" void kernel_launch(void* const* d_in, const int* in_sizes, int n_in,
                              void* d_out, int out_size, void* d_ws, size_t ws_size,
                              hipStream_t stream)
{
    const float* x    = (const float*)d_in[0];
    const float* inp  = (const float*)d_in[1];
    const float* Wqkv = (const float*)d_in[2];
    const float* bqkv = (const float*)d_in[3];
    const float* Wo   = (const float*)d_in[4];
    const float* bo   = (const float*)d_in[5];

    float* out_o   = (float*)d_out;                    // [8,1024,512]
    float* out_att = out_o + (size_t)8 * 1024 * 512;   // [8,8,1024,1024]

    char* ws = (char*)d_ws;
    __bf16* xc    = (__bf16*)(ws + 0);
    __bf16* wq    = (__bf16*)(ws + 9437184);
    __bf16* wo    = (__bf16*)(ws + 11206656);
    __bf16* q_ws  = (__bf16*)(ws + 11730944);
    __bf16* k_ws  = (__bf16*)(ws + 20119552);
    __bf16* vt_ws = (__bf16*)(ws + 28508160);
    __bf16* vals  = (__bf16*)(ws + 36896768);

    k_convert<<<2864, 256, 0, stream>>>(x, inp, Wqkv, Wo, xc, wq, wo);
    k_qkv_gemm<<<dim3(64, 12), 256, 0, stream>>>(xc, wq, bqkv, q_ws, k_ws, vt_ws);
    k_attn<<<4096, 256, 0, stream>>>(q_ws, k_ws, vt_ws, out_att, vals);
    k_out_gemm<<<dim3(64, 4), 256, 0, stream>>>(vals, wo, bo, out_o);
}